// Round 1
// 317.926 us; speedup vs baseline: 1.0468x; 1.0468x over previous
//
#include <hip/hip_runtime.h>
#include <hip/hip_bf16.h>

#define N_NODES 100000
#define N_EDGES 1600000
#define IN_CH 256
#define OUT_CH 128

#define BSZ 512            // nodes per bucket (power of 2)
#define NBUCK 196          // ceil(N_NODES / BSZ)
#define CHH 6400           // edges per block, pass-A histogram
#define CSC 8192           // edges per block, pass-A scatter

#define GEMM_ROWS 32       // rows per block

typedef __attribute__((ext_vector_type(8))) short short8;
typedef __attribute__((ext_vector_type(4))) float floatx4;

union bfu { __hip_bfloat16 b; unsigned short u; };

__device__ inline unsigned short f2bf(float v) {
    bfu cv; cv.b = __float2bfloat16(v); return cv.u;
}
__device__ inline float bf2f(unsigned short u) {
    bfu cv; cv.u = u; return __bfloat162float(cv.b);
}

// ---------- pass A: coarse bucket partition (bucket = dst >> 9) ----------
__global__ __launch_bounds__(256) void pa_zero(int* bhist) {
    int t = threadIdx.x;
    if (t < NBUCK) bhist[t] = 0;
}

__global__ __launch_bounds__(256) void pa_hist(const int* __restrict__ cols,
                                               int* __restrict__ bhist) {
    __shared__ int lh[NBUCK];
    int t = threadIdx.x;
    if (t < NBUCK) lh[t] = 0;
    __syncthreads();
    int s0 = blockIdx.x * CHH;
    int e1 = min(N_EDGES, s0 + CHH);
    for (int i = s0 + t; i < e1; i += 256) atomicAdd(&lh[cols[i] >> 9], 1);
    __syncthreads();
    if (t < NBUCK && lh[t]) atomicAdd(&bhist[t], lh[t]);
}

__global__ __launch_bounds__(256) void pa_scan(const int* __restrict__ bhist,
                                               int* __restrict__ bbase,
                                               int* __restrict__ bcursor) {
    __shared__ int s[256];
    int t = threadIdx.x;
    int v = (t < NBUCK) ? bhist[t] : 0;
    s[t] = v;
    __syncthreads();
    for (int off = 1; off < 256; off <<= 1) {
        int u = (t >= off) ? s[t - off] : 0;
        __syncthreads();
        s[t] += u;
        __syncthreads();
    }
    if (t < NBUCK) {
        int e = s[t] - v;   // exclusive
        bbase[t] = e;
        bcursor[t] = e;
    }
}

// per-block LDS count -> one reservation per bucket -> run-contiguous writes
__global__ __launch_bounds__(256) void pa_scatter(const int* __restrict__ rows,
                                                  const int* __restrict__ cols,
                                                  int* __restrict__ bcursor,
                                                  unsigned* __restrict__ ebuf) {
    __shared__ int lcnt[NBUCK];
    __shared__ int lbase[NBUCK];
    int t = threadIdx.x;
    if (t < NBUCK) lcnt[t] = 0;
    __syncthreads();
    int s0 = blockIdx.x * CSC;
    int e1 = min(N_EDGES, s0 + CSC);
    for (int i = s0 + t; i < e1; i += 256) atomicAdd(&lcnt[cols[i] >> 9], 1);
    __syncthreads();
    if (t < NBUCK) {
        int c = lcnt[t];
        lbase[t] = c ? atomicAdd(&bcursor[t], c) : 0;
        lcnt[t] = 0;
    }
    __syncthreads();
    for (int i = s0 + t; i < e1; i += 256) {
        int c = cols[i], r = rows[i];
        int bk = c >> 9;
        int rank = atomicAdd(&lcnt[bk], 1);
        ebuf[lbase[bk] + rank] = ((unsigned)(c & (BSZ - 1)) << 17) | (unsigned)r;
    }
}

// ---------- pass B: per-bucket fine sort + cnt/base/dinv, all in LDS ----------
__global__ __launch_bounds__(256) void pb_build(const unsigned* __restrict__ ebuf,
                                                const int* __restrict__ bhist,
                                                const int* __restrict__ bbase,
                                                int* __restrict__ cnt,
                                                int* __restrict__ base,
                                                float* __restrict__ dinv,
                                                int* __restrict__ es) {
    __shared__ int nh[BSZ];
    __shared__ int sc[BSZ];
    __shared__ int lcur[BSZ];
    int t = threadIdx.x;
    int bk = blockIdx.x;
    int bb = bbase[bk];
    int bc = bhist[bk];
    nh[t] = 0; nh[t + 256] = 0;
    lcur[t] = 0; lcur[t + 256] = 0;
    __syncthreads();
    for (int i = t; i < bc; i += 256) atomicAdd(&nh[ebuf[bb + i] >> 17], 1);
    __syncthreads();
    sc[t] = nh[t]; sc[t + 256] = nh[t + 256];
    __syncthreads();
    for (int off = 1; off < BSZ; off <<= 1) {
        int v0 = (t >= off) ? sc[t - off] : 0;
        int i1 = t + 256;
        int v1 = (i1 >= off) ? sc[i1 - off] : 0;
        __syncthreads();
        sc[t] += v0; sc[i1] += v1;
        __syncthreads();
    }
#pragma unroll
    for (int q = 0; q < 2; ++q) {
        int dl = t + q * 256;
        int node = bk * BSZ + dl;
        if (node < N_NODES) {
            int c = nh[dl];
            cnt[node] = c;
            base[node] = bb + sc[dl] - c;   // exclusive within bucket + bucket base
            dinv[node] = rsqrtf((float)(c + 1));
        }
    }
    for (int i = t; i < bc; i += 256) {
        unsigned v = ebuf[bb + i];
        int dl = v >> 17;
        int src = (int)(v & 0x1FFFFu);
        int rank = atomicAdd(&lcur[dl], 1);
        es[bb + sc[dl] - nh[dl] + rank] = src;
    }
}

// ---------- W (fp32, [256,128]) -> MFMA-fragment-packed bf16 hi/lo ----------
__global__ void k_prep_w(const float* __restrict__ W,
                         unsigned short* __restrict__ wb_hi,
                         unsigned short* __restrict__ wb_lo) {
    int t = blockIdx.x * 256 + threadIdx.x;   // 0..32767
    if (t >= IN_CH * OUT_CH) return;
    int j = t & 7;
    int lane = (t >> 3) & 63;
    int s = (t >> 9) & 7;
    int nt = t >> 12;
    int k = s * 32 + (lane >> 4) * 8 + j;
    int n = nt * 16 + (lane & 15);
    float w = W[k * OUT_CH + n];
    unsigned short hi = f2bf(w);
    wb_hi[t] = hi;
    wb_lo[t] = f2bf(w - bf2f(hi));
}

// ---------- h = x @ W  (fp32 in via split-bf16 MFMA) ----------
// Output: hbs (bf16, pre-scaled by dinv[row]).  fp32 h is no longer stored:
// the self-loop term in aggregation is reconstructed from hbs (one more
// bf16-rounded term among ~17 equal-variance terms).
// A-tile conversion is cooperative: each of the 512 threads converts exactly
// 2 MFMA fragment slots (16 elements) ONCE; all 8 waves share them via LDS.
// Fragment-packed layout [ms][s][lane][8] makes both the ds_write and the
// ds_read_b128 lane-consecutive (conflict-free).
__global__ __launch_bounds__(512) void k_gemm(const float* __restrict__ x,
                                              const unsigned short* __restrict__ wb_hi,
                                              const unsigned short* __restrict__ wb_lo,
                                              const float* __restrict__ dinv,
                                              unsigned short* __restrict__ hbs) {
    __shared__ short8 xbh[1024];   // 16 KiB: [ms(2)][s(8)][lane(64)] x 8 shorts
    __shared__ short8 xbl[1024];   // 16 KiB
    int t = threadIdx.x;
    int wv = t >> 6;        // 0..7 = n-tile
    int lane = t & 63;
    int row0 = blockIdx.x * GEMM_ROWS;

    // B fragments (L2-resident, 64 KiB each): issue loads early
    short8 Bh[8], Bl[8];
    const short8* bhp = (const short8*)wb_hi + (size_t)wv * 8 * 64 + lane;
    const short8* blp = (const short8*)wb_lo + (size_t)wv * 8 * 64 + lane;
#pragma unroll
    for (int s = 0; s < 8; ++s) {
        Bh[s] = bhp[s * 64];
        Bl[s] = blp[s * 64];
    }

    // cooperative fp32 -> split-bf16 conversion, 2 fragment slots per thread
#pragma unroll
    for (int q = 0; q < 2; ++q) {
        int slot = q * 512 + t;
        int ms = slot >> 9;
        int s  = (slot >> 6) & 7;
        int l  = slot & 63;
        int row = row0 + ms * 16 + (l & 15);
        int col = s * 32 + (l >> 4) * 8;
        const float4* xp = (const float4*)(x + (size_t)row * IN_CH + col);
        float4 v0 = xp[0];
        float4 v1 = xp[1];
        float xv[8] = {v0.x, v0.y, v0.z, v0.w, v1.x, v1.y, v1.z, v1.w};
        short8 hh, ll;
#pragma unroll
        for (int j = 0; j < 8; ++j) {
            unsigned short hi = f2bf(xv[j]);
            hh[j] = (short)hi;
            ll[j] = (short)f2bf(xv[j] - bf2f(hi));
        }
        xbh[slot] = hh;
        xbl[slot] = ll;
    }
    __syncthreads();

    int r15 = lane & 15;
    int quad = lane >> 4;

    floatx4 acc[2];
#pragma unroll
    for (int ms = 0; ms < 2; ++ms) {
        acc[ms] = (floatx4){0.f, 0.f, 0.f, 0.f};
#pragma unroll
        for (int s = 0; s < 8; ++s) {
            short8 ah = xbh[(ms * 8 + s) * 64 + lane];
            short8 al = xbl[(ms * 8 + s) * 64 + lane];
            acc[ms] = __builtin_amdgcn_mfma_f32_16x16x32_bf16(ah, Bh[s], acc[ms], 0, 0, 0);
            acc[ms] = __builtin_amdgcn_mfma_f32_16x16x32_bf16(ah, Bl[s], acc[ms], 0, 0, 0);
            acc[ms] = __builtin_amdgcn_mfma_f32_16x16x32_bf16(al, Bh[s], acc[ms], 0, 0, 0);
        }
    }

#pragma unroll
    for (int ms = 0; ms < 2; ++ms)
#pragma unroll
        for (int r = 0; r < 4; ++r) {
            int row = row0 + ms * 16 + quad * 4 + r;
            size_t idx = (size_t)row * OUT_CH + wv * 16 + r15;
            hbs[idx] = f2bf(acc[ms][r] * dinv[row]);
        }
}

// ---------- fused gather-aggregate + minmax scale + L2 normalize ----------
// Self term comes from hbs[node] (bf16): acc = dn * (hbs[node] + sum hbs[src]) + b.
// Edge ids are preloaded in one coalesced load (es[st+lane]) and broadcast
// via v_readlane; gathers unrolled 8-deep for MLP.
__global__ __launch_bounds__(256) void k_agg_fin(const unsigned short* __restrict__ hbs,
                                                 const float* __restrict__ dinv,
                                                 const int* __restrict__ es,
                                                 const int* __restrict__ base,
                                                 const int* __restrict__ cnt,
                                                 const float* __restrict__ b,
                                                 float* __restrict__ out) {
    int node = (blockIdx.x * 256 + threadIdx.x) >> 6;   // wave-uniform
    int lane = threadIdx.x & 63;
    if (node >= N_NODES) return;

    const unsigned* hp = (const unsigned*)hbs;
    float dn = dinv[node];
    float2 bv = ((const float2*)b)[lane];

    int st = __builtin_amdgcn_readfirstlane(base[node]);
    int d  = __builtin_amdgcn_readfirstlane(cnt[node]);

    // self row (pre-scaled by dinv[node]):  dn * this = h[node] * dn^2
    unsigned gs = hp[(size_t)node * 64 + lane];
    float ex = __uint_as_float(gs << 16);
    float ey = __uint_as_float(gs & 0xffff0000u);

    // preload up to 64 edge ids in one coalesced read
    int sid = (lane < d) ? es[st + lane] : 0;
    int dc = d < 64 ? d : 64;

    int j = 0;
    for (; j + 8 <= dc; j += 8) {
        int s0 = __builtin_amdgcn_readlane(sid, j + 0);
        int s1 = __builtin_amdgcn_readlane(sid, j + 1);
        int s2 = __builtin_amdgcn_readlane(sid, j + 2);
        int s3 = __builtin_amdgcn_readlane(sid, j + 3);
        int s4 = __builtin_amdgcn_readlane(sid, j + 4);
        int s5 = __builtin_amdgcn_readlane(sid, j + 5);
        int s6 = __builtin_amdgcn_readlane(sid, j + 6);
        int s7 = __builtin_amdgcn_readlane(sid, j + 7);
        unsigned g0 = hp[(size_t)s0 * 64 + lane];
        unsigned g1 = hp[(size_t)s1 * 64 + lane];
        unsigned g2 = hp[(size_t)s2 * 64 + lane];
        unsigned g3 = hp[(size_t)s3 * 64 + lane];
        unsigned g4 = hp[(size_t)s4 * 64 + lane];
        unsigned g5 = hp[(size_t)s5 * 64 + lane];
        unsigned g6 = hp[(size_t)s6 * 64 + lane];
        unsigned g7 = hp[(size_t)s7 * 64 + lane];
        ex += __uint_as_float(g0 << 16);  ey += __uint_as_float(g0 & 0xffff0000u);
        ex += __uint_as_float(g1 << 16);  ey += __uint_as_float(g1 & 0xffff0000u);
        ex += __uint_as_float(g2 << 16);  ey += __uint_as_float(g2 & 0xffff0000u);
        ex += __uint_as_float(g3 << 16);  ey += __uint_as_float(g3 & 0xffff0000u);
        ex += __uint_as_float(g4 << 16);  ey += __uint_as_float(g4 & 0xffff0000u);
        ex += __uint_as_float(g5 << 16);  ey += __uint_as_float(g5 & 0xffff0000u);
        ex += __uint_as_float(g6 << 16);  ey += __uint_as_float(g6 & 0xffff0000u);
        ex += __uint_as_float(g7 << 16);  ey += __uint_as_float(g7 & 0xffff0000u);
    }
    for (; j + 4 <= dc; j += 4) {
        int s0 = __builtin_amdgcn_readlane(sid, j + 0);
        int s1 = __builtin_amdgcn_readlane(sid, j + 1);
        int s2 = __builtin_amdgcn_readlane(sid, j + 2);
        int s3 = __builtin_amdgcn_readlane(sid, j + 3);
        unsigned g0 = hp[(size_t)s0 * 64 + lane];
        unsigned g1 = hp[(size_t)s1 * 64 + lane];
        unsigned g2 = hp[(size_t)s2 * 64 + lane];
        unsigned g3 = hp[(size_t)s3 * 64 + lane];
        ex += __uint_as_float(g0 << 16);  ey += __uint_as_float(g0 & 0xffff0000u);
        ex += __uint_as_float(g1 << 16);  ey += __uint_as_float(g1 & 0xffff0000u);
        ex += __uint_as_float(g2 << 16);  ey += __uint_as_float(g2 & 0xffff0000u);
        ex += __uint_as_float(g3 << 16);  ey += __uint_as_float(g3 & 0xffff0000u);
    }
    for (; j < dc; ++j) {
        int s0 = __builtin_amdgcn_readlane(sid, j);
        unsigned g0 = hp[(size_t)s0 * 64 + lane];
        ex += __uint_as_float(g0 << 16);  ey += __uint_as_float(g0 & 0xffff0000u);
    }
    // overflow path for degree > 64 (essentially never hit at mean degree 16)
    for (; j < d; ++j) {
        int s0 = __builtin_amdgcn_readfirstlane(es[st + j]);
        unsigned g0 = hp[(size_t)s0 * 64 + lane];
        ex += __uint_as_float(g0 << 16);  ey += __uint_as_float(g0 & 0xffff0000u);
    }

    float2 acc;
    acc.x = dn * ex + bv.x;
    acc.y = dn * ey + bv.y;

    // min-max scale
    float lmin = fminf(acc.x, acc.y), lmax = fmaxf(acc.x, acc.y);
#pragma unroll
    for (int m = 32; m; m >>= 1) {
        lmin = fminf(lmin, __shfl_xor(lmin, m, 64));
        lmax = fmaxf(lmax, __shfl_xor(lmax, m, 64));
    }
    float scale = 1.0f / (lmax - lmin);
    float zx = (acc.x - lmin) * scale;
    float zy = (acc.y - lmin) * scale;
    // L2 normalize
    float ss = zx * zx + zy * zy;
#pragma unroll
    for (int m = 32; m; m >>= 1) ss += __shfl_xor(ss, m, 64);
    float inv = 1.0f / fmaxf(sqrtf(ss), 1e-12f);
    float2 o;
    o.x = zx * inv;
    o.y = zy * inv;
    ((float2*)(out + (size_t)node * OUT_CH))[lane] = o;
}

extern "C" void kernel_launch(void* const* d_in, const int* in_sizes, int n_in,
                              void* d_out, int out_size, void* d_ws, size_t ws_size,
                              hipStream_t stream) {
    const float* x = (const float*)d_in[0];        // fp32 [N, 256]
    const int* ei = (const int*)d_in[1];           // int32 [2, E]
    const float* W = (const float*)d_in[2];        // fp32 [256, 128]
    const float* b = (const float*)d_in[3];        // fp32 [128]
    float* out = (float*)d_out;                    // fp32 [N, 128]

    char* ws = (char*)d_ws;
    size_t o = 0;
    auto alloc = [&](size_t bytes) { void* p = ws + o; o = (o + bytes + 255) & ~(size_t)255; return p; };
    float* dinv    = (float*)alloc((size_t)N_NODES * 4);
    int*   cnt     = (int*)  alloc((size_t)N_NODES * 4);
    int*   base    = (int*)  alloc((size_t)N_NODES * 4);
    int*   bhist   = (int*)  alloc(NBUCK * 4);
    int*   bbase   = (int*)  alloc(NBUCK * 4);
    int*   bcursor = (int*)  alloc(NBUCK * 4);
    unsigned short* wb_hi = (unsigned short*)alloc((size_t)IN_CH * OUT_CH * 2);
    unsigned short* wb_lo = (unsigned short*)alloc((size_t)IN_CH * OUT_CH * 2);
    unsigned short* hbs = (unsigned short*)alloc((size_t)N_NODES * OUT_CH * 2);
    unsigned* ebuf = (unsigned*)alloc((size_t)N_EDGES * 4);
    int*   es      = (int*)  alloc((size_t)N_EDGES * 4);

    const int* rows = ei;
    const int* cols = ei + N_EDGES;

    // CSR build (two-level bucketed counting sort)
    pa_zero<<<1, 256, 0, stream>>>(bhist);
    pa_hist<<<(N_EDGES + CHH - 1) / CHH, 256, 0, stream>>>(cols, bhist);
    pa_scan<<<1, 256, 0, stream>>>(bhist, bbase, bcursor);
    pa_scatter<<<(N_EDGES + CSC - 1) / CSC, 256, 0, stream>>>(rows, cols, bcursor, ebuf);
    pb_build<<<NBUCK, 256, 0, stream>>>(ebuf, bhist, bbase, cnt, base, dinv, es);

    // GEMM
    k_prep_w<<<(IN_CH * OUT_CH + 255) / 256, 256, 0, stream>>>(W, wb_hi, wb_lo);
    k_gemm<<<N_NODES / GEMM_ROWS, 512, 0, stream>>>(x, wb_hi, wb_lo, dinv, hbs);

    // fused aggregate + scale + normalize
    k_agg_fin<<<(N_NODES + 3) / 4, 256, 0, stream>>>(hbs, dinv, es, base, cnt, b, out);
}

// Round 2
// 304.641 us; speedup vs baseline: 1.0924x; 1.0436x over previous
//
#include <hip/hip_runtime.h>
#include <hip/hip_bf16.h>

#define N_NODES 100000
#define N_EDGES 1600000
#define IN_CH 256
#define OUT_CH 128

#define BSZ 512            // nodes per bucket (power of 2)
#define NBUCK 196          // ceil(N_NODES / BSZ)
#define BCAP 9216          // bucket capacity: mean 8192, sd ~90 -> 11+ sigma headroom
#define CSC 8192           // edges per block, scatter

#define GEMM_ROWS 32       // rows per block

typedef __attribute__((ext_vector_type(8))) short short8;
typedef __attribute__((ext_vector_type(4))) float floatx4;
typedef __attribute__((ext_vector_type(2))) float float2v;

union bfu { __hip_bfloat16 b; unsigned short u; };

__device__ inline unsigned short f2bf(float v) {
    bfu cv; cv.b = __float2bfloat16(v); return cv.u;
}
__device__ inline float bf2f(unsigned short u) {
    bfu cv; cv.u = u; return __bfloat162float(cv.b);
}

// unpack a packed bf16 pair and accumulate both channels with one v_pk_add_f32
__device__ inline void pkacc(float2v& acc, unsigned g) {
    float2v v;
    v.x = __uint_as_float(g << 16);
    v.y = __uint_as_float(g & 0xffff0000u);
    asm("v_pk_add_f32 %0, %1, %2" : "=v"(acc) : "v"(v), "v"(acc));
}

// ---------- single-pass bucket scatter (capacity-strided buckets) ----------
// bucket = dst >> 9.  Per-block LDS count -> one global reservation per
// bucket -> run-contiguous writes at bk*BCAP + rank.  No histogram/scan pass.
__global__ __launch_bounds__(256) void pa_scatter(const int* __restrict__ rows,
                                                  const int* __restrict__ cols,
                                                  int* __restrict__ bcursor,
                                                  unsigned* __restrict__ ebuf) {
    __shared__ int lcnt[NBUCK];
    __shared__ int lbase[NBUCK];
    int t = threadIdx.x;
    if (t < NBUCK) lcnt[t] = 0;
    __syncthreads();
    int s0 = blockIdx.x * CSC;
    int e1 = min(N_EDGES, s0 + CSC);
    for (int i = s0 + t; i < e1; i += 256) atomicAdd(&lcnt[cols[i] >> 9], 1);
    __syncthreads();
    if (t < NBUCK) {
        int c = lcnt[t];
        lbase[t] = c ? atomicAdd(&bcursor[t], c) : 0;
        lcnt[t] = 0;
    }
    __syncthreads();
    for (int i = s0 + t; i < e1; i += 256) {
        int c = cols[i], r = rows[i];
        int bk = c >> 9;
        int rank = atomicAdd(&lcnt[bk], 1);
        ebuf[bk * BCAP + lbase[bk] + rank] = ((unsigned)(c & (BSZ - 1)) << 17) | (unsigned)r;
    }
}

// ---------- per-bucket fine sort + cnt/base/dinv, all in LDS ----------
// After pa_scatter, bcursor[bk] holds the bucket's edge count.
// es entries are stored as BYTE offsets into hbs (src * 256).
__global__ __launch_bounds__(256) void pb_build(const unsigned* __restrict__ ebuf,
                                                const int* __restrict__ bcursor,
                                                int* __restrict__ cnt,
                                                int* __restrict__ base,
                                                float* __restrict__ dinv,
                                                int* __restrict__ es) {
    __shared__ int nh[BSZ];
    __shared__ int sc[BSZ];
    __shared__ int lcur[BSZ];
    int t = threadIdx.x;
    int bk = blockIdx.x;
    int bb = bk * BCAP;
    int bc = bcursor[bk];
    nh[t] = 0; nh[t + 256] = 0;
    lcur[t] = 0; lcur[t + 256] = 0;
    __syncthreads();
    for (int i = t; i < bc; i += 256) atomicAdd(&nh[ebuf[bb + i] >> 17], 1);
    __syncthreads();
    sc[t] = nh[t]; sc[t + 256] = nh[t + 256];
    __syncthreads();
    for (int off = 1; off < BSZ; off <<= 1) {
        int v0 = (t >= off) ? sc[t - off] : 0;
        int i1 = t + 256;
        int v1 = (i1 >= off) ? sc[i1 - off] : 0;
        __syncthreads();
        sc[t] += v0; sc[i1] += v1;
        __syncthreads();
    }
#pragma unroll
    for (int q = 0; q < 2; ++q) {
        int dl = t + q * 256;
        int node = bk * BSZ + dl;
        if (node < N_NODES) {
            int c = nh[dl];
            cnt[node] = c;
            base[node] = bb + sc[dl] - c;   // exclusive within bucket + strided bucket base
            dinv[node] = rsqrtf((float)(c + 1));
        }
    }
    for (int i = t; i < bc; i += 256) {
        unsigned v = ebuf[bb + i];
        int dl = v >> 17;
        int src = (int)(v & 0x1FFFFu);
        int rank = atomicAdd(&lcur[dl], 1);
        es[bb + sc[dl] - nh[dl] + rank] = src << 8;   // byte offset into hbs
    }
}

// ---------- W (fp32, [256,128]) -> MFMA-fragment-packed bf16 hi/lo ----------
__global__ void k_prep_w(const float* __restrict__ W,
                         unsigned short* __restrict__ wb_hi,
                         unsigned short* __restrict__ wb_lo) {
    int t = blockIdx.x * 256 + threadIdx.x;   // 0..32767
    if (t >= IN_CH * OUT_CH) return;
    int j = t & 7;
    int lane = (t >> 3) & 63;
    int s = (t >> 9) & 7;
    int nt = t >> 12;
    int k = s * 32 + (lane >> 4) * 8 + j;
    int n = nt * 16 + (lane & 15);
    float w = W[k * OUT_CH + n];
    unsigned short hi = f2bf(w);
    wb_hi[t] = hi;
    wb_lo[t] = f2bf(w - bf2f(hi));
}

// ---------- h = x @ W  (fp32 in via split-bf16 MFMA) ----------
// Output: hbs (bf16, pre-scaled by dinv[row]).  Cooperative conversion:
// each of the 512 threads converts 2 MFMA fragment slots once; all 8 waves
// share via LDS, fragment-packed [ms][s][lane][8].
__global__ __launch_bounds__(512) void k_gemm(const float* __restrict__ x,
                                              const unsigned short* __restrict__ wb_hi,
                                              const unsigned short* __restrict__ wb_lo,
                                              const float* __restrict__ dinv,
                                              unsigned short* __restrict__ hbs) {
    __shared__ short8 xbh[1024];   // 16 KiB
    __shared__ short8 xbl[1024];   // 16 KiB
    int t = threadIdx.x;
    int wv = t >> 6;        // 0..7 = n-tile
    int lane = t & 63;
    int row0 = blockIdx.x * GEMM_ROWS;

    // B fragments (L2-resident): issue loads early
    short8 Bh[8], Bl[8];
    const short8* bhp = (const short8*)wb_hi + (size_t)wv * 8 * 64 + lane;
    const short8* blp = (const short8*)wb_lo + (size_t)wv * 8 * 64 + lane;
#pragma unroll
    for (int s = 0; s < 8; ++s) {
        Bh[s] = bhp[s * 64];
        Bl[s] = blp[s * 64];
    }

    // cooperative fp32 -> split-bf16 conversion, 2 fragment slots per thread
#pragma unroll
    for (int q = 0; q < 2; ++q) {
        int slot = q * 512 + t;
        int ms = slot >> 9;
        int s  = (slot >> 6) & 7;
        int l  = slot & 63;
        int row = row0 + ms * 16 + (l & 15);
        int col = s * 32 + (l >> 4) * 8;
        const float4* xp = (const float4*)(x + (size_t)row * IN_CH + col);
        float4 v0 = xp[0];
        float4 v1 = xp[1];
        float xv[8] = {v0.x, v0.y, v0.z, v0.w, v1.x, v1.y, v1.z, v1.w};
        short8 hh, ll;
#pragma unroll
        for (int j = 0; j < 8; ++j) {
            unsigned short hi = f2bf(xv[j]);
            hh[j] = (short)hi;
            ll[j] = (short)f2bf(xv[j] - bf2f(hi));
        }
        xbh[slot] = hh;
        xbl[slot] = ll;
    }
    __syncthreads();

    int r15 = lane & 15;
    int quad = lane >> 4;

    floatx4 acc[2];
#pragma unroll
    for (int ms = 0; ms < 2; ++ms) {
        acc[ms] = (floatx4){0.f, 0.f, 0.f, 0.f};
#pragma unroll
        for (int s = 0; s < 8; ++s) {
            short8 ah = xbh[(ms * 8 + s) * 64 + lane];
            short8 al = xbl[(ms * 8 + s) * 64 + lane];
            acc[ms] = __builtin_amdgcn_mfma_f32_16x16x32_bf16(ah, Bh[s], acc[ms], 0, 0, 0);
            acc[ms] = __builtin_amdgcn_mfma_f32_16x16x32_bf16(ah, Bl[s], acc[ms], 0, 0, 0);
            acc[ms] = __builtin_amdgcn_mfma_f32_16x16x32_bf16(al, Bh[s], acc[ms], 0, 0, 0);
        }
    }

#pragma unroll
    for (int ms = 0; ms < 2; ++ms)
#pragma unroll
        for (int r = 0; r < 4; ++r) {
            int row = row0 + ms * 16 + quad * 4 + r;
            size_t idx = (size_t)row * OUT_CH + wv * 16 + r15;
            hbs[idx] = f2bf(acc[ms][r] * dinv[row]);
        }
}

// ---------- fused gather-aggregate + minmax scale + L2 normalize ----------
// One wave per node.  es holds byte offsets (src*256); edge ids preloaded in
// one coalesced read and broadcast via v_readlane; gathers 16-deep for MLP;
// both channels accumulated with one v_pk_add_f32 per packed word.
__global__ __launch_bounds__(256) void k_agg_fin(const unsigned short* __restrict__ hbs,
                                                 const float* __restrict__ dinv,
                                                 const int* __restrict__ es,
                                                 const int* __restrict__ base,
                                                 const int* __restrict__ cnt,
                                                 const float* __restrict__ b,
                                                 float* __restrict__ out) {
    int node = (blockIdx.x * 256 + threadIdx.x) >> 6;   // wave-uniform
    int lane = threadIdx.x & 63;
    if (node >= N_NODES) return;

    const char* hb = (const char*)hbs;
    float dn = dinv[node];
    float2 bv = ((const float2*)b)[lane];

    int st = __builtin_amdgcn_readfirstlane(base[node]);
    int d  = __builtin_amdgcn_readfirstlane(cnt[node]);

    // self row (pre-scaled by dinv[node]):  dn * this = h[node] * dn^2
    unsigned gs = *((const unsigned*)(hb + (size_t)node * 256) + lane);
    float2v acc;
    acc.x = __uint_as_float(gs << 16);
    acc.y = __uint_as_float(gs & 0xffff0000u);

    // preload up to 64 edge byte-offsets in one coalesced read
    int sid = (lane < d) ? es[st + lane] : 0;
    int dc = d < 64 ? d : 64;

    int j = 0;
    for (; j + 16 <= dc; j += 16) {
        unsigned g[16];
#pragma unroll
        for (int k = 0; k < 16; ++k) {
            int off = __builtin_amdgcn_readlane(sid, j + k);
            g[k] = *((const unsigned*)(hb + (unsigned)off) + lane);
        }
#pragma unroll
        for (int k = 0; k < 16; ++k) pkacc(acc, g[k]);
    }
    if (j + 8 <= dc) {
        unsigned g[8];
#pragma unroll
        for (int k = 0; k < 8; ++k) {
            int off = __builtin_amdgcn_readlane(sid, j + k);
            g[k] = *((const unsigned*)(hb + (unsigned)off) + lane);
        }
#pragma unroll
        for (int k = 0; k < 8; ++k) pkacc(acc, g[k]);
        j += 8;
    }
    if (j + 4 <= dc) {
        unsigned g[4];
#pragma unroll
        for (int k = 0; k < 4; ++k) {
            int off = __builtin_amdgcn_readlane(sid, j + k);
            g[k] = *((const unsigned*)(hb + (unsigned)off) + lane);
        }
#pragma unroll
        for (int k = 0; k < 4; ++k) pkacc(acc, g[k]);
        j += 4;
    }
    for (; j < dc; ++j) {
        int off = __builtin_amdgcn_readlane(sid, j);
        pkacc(acc, *((const unsigned*)(hb + (unsigned)off) + lane));
    }
    // overflow path for degree > 64 (essentially never hit at mean degree 16)
    for (; j < d; ++j) {
        int off = __builtin_amdgcn_readfirstlane(es[st + j]);
        pkacc(acc, *((const unsigned*)(hb + (unsigned)off) + lane));
    }

    float ax = dn * acc.x + bv.x;
    float ay = dn * acc.y + bv.y;

    // min-max scale
    float lmin = fminf(ax, ay), lmax = fmaxf(ax, ay);
#pragma unroll
    for (int m = 32; m; m >>= 1) {
        lmin = fminf(lmin, __shfl_xor(lmin, m, 64));
        lmax = fmaxf(lmax, __shfl_xor(lmax, m, 64));
    }
    float scale = 1.0f / (lmax - lmin);
    float zx = (ax - lmin) * scale;
    float zy = (ay - lmin) * scale;
    // L2 normalize
    float ss = zx * zx + zy * zy;
#pragma unroll
    for (int m = 32; m; m >>= 1) ss += __shfl_xor(ss, m, 64);
    float inv = 1.0f / fmaxf(sqrtf(ss), 1e-12f);
    float2 o;
    o.x = zx * inv;
    o.y = zy * inv;
    ((float2*)(out + (size_t)node * OUT_CH))[lane] = o;
}

extern "C" void kernel_launch(void* const* d_in, const int* in_sizes, int n_in,
                              void* d_out, int out_size, void* d_ws, size_t ws_size,
                              hipStream_t stream) {
    const float* x = (const float*)d_in[0];        // fp32 [N, 256]
    const int* ei = (const int*)d_in[1];           // int32 [2, E]
    const float* W = (const float*)d_in[2];        // fp32 [256, 128]
    const float* b = (const float*)d_in[3];        // fp32 [128]
    float* out = (float*)d_out;                    // fp32 [N, 128]

    char* ws = (char*)d_ws;
    size_t o = 0;
    auto alloc = [&](size_t bytes) { void* p = ws + o; o = (o + bytes + 255) & ~(size_t)255; return p; };
    float* dinv    = (float*)alloc((size_t)N_NODES * 4);
    int*   cnt     = (int*)  alloc((size_t)N_NODES * 4);
    int*   base    = (int*)  alloc((size_t)N_NODES * 4);
    int*   bcursor = (int*)  alloc(NBUCK * 4);
    unsigned short* wb_hi = (unsigned short*)alloc((size_t)IN_CH * OUT_CH * 2);
    unsigned short* wb_lo = (unsigned short*)alloc((size_t)IN_CH * OUT_CH * 2);
    unsigned short* hbs = (unsigned short*)alloc((size_t)N_NODES * OUT_CH * 2);
    unsigned* ebuf = (unsigned*)alloc((size_t)NBUCK * BCAP * 4);
    int*   es      = (int*)  alloc((size_t)NBUCK * BCAP * 4);

    const int* rows = ei;
    const int* cols = ei + N_EDGES;

    // CSR build: single-pass capacity-strided bucket scatter + per-bucket sort
    hipMemsetAsync(bcursor, 0, NBUCK * sizeof(int), stream);
    pa_scatter<<<(N_EDGES + CSC - 1) / CSC, 256, 0, stream>>>(rows, cols, bcursor, ebuf);
    pb_build<<<NBUCK, 256, 0, stream>>>(ebuf, bcursor, cnt, base, dinv, es);

    // GEMM
    k_prep_w<<<(IN_CH * OUT_CH + 255) / 256, 256, 0, stream>>>(W, wb_hi, wb_lo);
    k_gemm<<<N_NODES / GEMM_ROWS, 512, 0, stream>>>(x, wb_hi, wb_lo, dinv, hbs);

    // fused aggregate + scale + normalize
    k_agg_fin<<<(N_NODES + 3) / 4, 256, 0, stream>>>(hbs, dinv, es, base, cnt, b, out);
}